// Round 1
// baseline (157.631 us; speedup 1.0000x reference)
//
#include <hip/hip_runtime.h>

#define NK 21      // classes
#define NC 256     // channels
#define NSRC 64    // source h/w
#define NOUT 256   // mask h/w
#define NB 8       // batch
#define NSTRIP 32  // 2 source rows per strip

// ---------------------------------------------------------------------------
// Main kernel: one block per (image b, strip of 2 source rows).
// Phase 1: build per-class bilinear-adjoint weight map W[21][2][64] in LDS
//          from the mask (LDS atomics), plus per-class pixel counts.
// Phase 2: sums[k][c] = sum_s W[k][s] * feats[b][c][s]  (thread = channel c)
// Epilogue: store per-strip partials (no global atomics) or atomic fallback.
// ---------------------------------------------------------------------------
__global__ __launch_bounds__(256)
void proto_main_kernel(const float* __restrict__ feats,
                       const int* __restrict__ masks,
                       float* __restrict__ psum,   // [B][NSTRIP][K][C] or [B][K][C] (atomic)
                       float* __restrict__ pcnt,   // [B][NSTRIP][K]    or [B][K]
                       int use_atomic) {
  __shared__ __align__(16) float Wl[NK * 128];  // [k][srow(2)][xs(64)]
  __shared__ int hist[NK];

  const int tid = threadIdx.x;
  const int strip = blockIdx.x;  // 0..31
  const int b = blockIdx.y;      // 0..7
  const int r0 = strip * 2;      // source row base

  for (int i = tid; i < NK * 128; i += 256) Wl[i] = 0.f;
  if (tid < NK) hist[tid] = 0;
  __syncthreads();

  // ---- Phase 1: scatter bilinear weights of every output pixel touching
  // source rows [r0, r0+2) into Wl, per class. ----
  int ylo = 4 * r0 - 2; if (ylo < 0) ylo = 0;
  int yhi = 4 * r0 + 9; if (yhi > NOUT - 1) yhi = NOUT - 1;
  const int npix = (yhi - ylo + 1) * NOUT;
  const int own_lo = 8 * strip;          // count-ownership rows [own_lo, own_lo+8)
  const int own_hi = own_lo + 8;

  for (int i = tid; i < npix; i += 256) {
    const int x = i & (NOUT - 1);
    const int y = ylo + (i >> 8);
    const int lbl = masks[((size_t)b * NOUT + y) * NOUT + x];
    if ((unsigned)lbl >= NK) continue;  // dump bucket / out-of-range: excluded

    // y taps: src coord = 0.25*y - 0.375
    const int ry = y >> 2, py = y & 3;
    const int j0y = (py < 2) ? ry - 1 : ry;
    const float fy = (py == 0) ? 0.625f : (py == 1) ? 0.875f
                   : (py == 2) ? 0.125f : 0.375f;
    // x taps
    const int rx = x >> 2, px = x & 3;
    const int j0x = (px < 2) ? rx - 1 : rx;
    const float fx = (px == 0) ? 0.625f : (px == 1) ? 0.875f
                   : (px == 2) ? 0.125f : 0.375f;

    const int cx0 = (j0x < 0) ? 0 : j0x;
    const int cx1 = (j0x + 1 > NSRC - 1) ? NSRC - 1 : j0x + 1;
    const float wx0 = 1.f - fx, wx1 = fx;

    const int ry0 = (j0y < 0) ? 0 : j0y;
    const int ry1 = (j0y + 1 > NSRC - 1) ? NSRC - 1 : j0y + 1;
    const float wy0 = 1.f - fy, wy1 = fy;

    float* Wk = &Wl[lbl * 128];
    const int sr0 = ry0 - r0, sr1 = ry1 - r0;
    if (sr0 >= 0 && sr0 < 2) {
      atomicAdd(&Wk[sr0 * 64 + cx0], wy0 * wx0);
      atomicAdd(&Wk[sr0 * 64 + cx1], wy0 * wx1);
    }
    if (sr1 >= 0 && sr1 < 2) {
      atomicAdd(&Wk[sr1 * 64 + cx0], wy1 * wx0);
      atomicAdd(&Wk[sr1 * 64 + cx1], wy1 * wx1);
    }
    if (y >= own_lo && y < own_hi) atomicAdd(&hist[lbl], 1);
  }
  __syncthreads();

  // ---- Phase 2: per-channel dot with the weight maps ----
  const int c = tid;  // 256 threads == 256 channels
  const float* fbase = feats + ((size_t)(b * NC + c) << 12) + (size_t)r0 * NSRC;

  float acc[NK];
#pragma unroll
  for (int k = 0; k < NK; ++k) acc[k] = 0.f;

  for (int s4 = 0; s4 < 128; s4 += 4) {
    const float4 f = *(const float4*)(fbase + s4);
#pragma unroll
    for (int k = 0; k < NK; ++k) {
      const float4 w = *(const float4*)(&Wl[k * 128 + s4]);
      float a = acc[k];
      a = fmaf(f.x, w.x, a);
      a = fmaf(f.y, w.y, a);
      a = fmaf(f.z, w.z, a);
      a = fmaf(f.w, w.w, a);
      acc[k] = a;
    }
  }

  // ---- Epilogue ----
  if (!use_atomic) {
    float* dst = psum + (((size_t)(b * NSTRIP + strip) * NK) * NC) + c;
#pragma unroll
    for (int k = 0; k < NK; ++k) dst[k * NC] = acc[k];
    if (tid < NK) pcnt[(size_t)(b * NSTRIP + strip) * NK + tid] = (float)hist[tid];
  } else {
#pragma unroll
    for (int k = 0; k < NK; ++k)
      atomicAdd(&psum[((size_t)b * NK + k) * NC + c], acc[k]);
    if (tid < NK) atomicAdd(&pcnt[(size_t)b * NK + tid], (float)hist[tid]);
  }
}

// ---------------------------------------------------------------------------
// Finalize: out[k][c] = (1/8) * sum_b sums[b][k][c] / (counts[b][k] + 1e-6)
// ---------------------------------------------------------------------------
__global__ __launch_bounds__(256)
void proto_final_kernel(const float* __restrict__ psum,
                        const float* __restrict__ pcnt,
                        float* __restrict__ out, int nstrip) {
  const int k = blockIdx.x;   // 0..20
  const int c = threadIdx.x;  // 0..255
  float acc = 0.f;
  for (int b = 0; b < NB; ++b) {
    float s = 0.f, cnt = 0.f;
    for (int st = 0; st < nstrip; ++st) {
      s += psum[((size_t)(b * nstrip + st) * NK + k) * NC + c];
      cnt += pcnt[(size_t)(b * nstrip + st) * NK + k];
    }
    acc += s / (cnt + 1e-6f);
  }
  out[(size_t)k * NC + c] = acc * 0.125f;
}

extern "C" void kernel_launch(void* const* d_in, const int* in_sizes, int n_in,
                              void* d_out, int out_size, void* d_ws, size_t ws_size,
                              hipStream_t stream) {
  const float* feats = (const float*)d_in[0];
  const int* masks = (const int*)d_in[1];
  float* out = (float*)d_out;

  const size_t needA = (size_t)NB * NSTRIP * NK * NC * 4 + (size_t)NB * NSTRIP * NK * 4;

  float* psum = (float*)d_ws;
  float* pcnt;
  int use_atomic, nstrip;
  if (ws_size >= needA) {
    use_atomic = 0;
    nstrip = NSTRIP;
    pcnt = psum + (size_t)NB * NSTRIP * NK * NC;
  } else {
    use_atomic = 1;
    nstrip = 1;
    pcnt = psum + (size_t)NB * NK * NC;
    hipMemsetAsync(d_ws, 0, ((size_t)NB * NK * NC + (size_t)NB * NK) * 4, stream);
  }

  proto_main_kernel<<<dim3(NSTRIP, NB), 256, 0, stream>>>(feats, masks, psum, pcnt, use_atomic);
  proto_final_kernel<<<dim3(NK), 256, 0, stream>>>(psum, pcnt, out, nstrip);
}

// Round 2
// 112.414 us; speedup vs baseline: 1.4022x; 1.4022x over previous
//
#include <hip/hip_runtime.h>

#define NK 21      // classes
#define NC 256     // channels
#define NSRC 64    // source h/w
#define NOUT 256   // mask h/w
#define NB 8       // batch
#define EPS 1e-6f

// ---------------------------------------------------------------------------
// Main kernel, templated on R = source rows per strip. Grid (NSRC/R, NB).
// Phase 1: bilinear-adjoint weight map W[21][R][64] in LDS from the mask.
// Phase 2: thread = channel; prefetch feats row into regs, dot with W.
// Epilogue: per-strip partials (no atomics).
// ---------------------------------------------------------------------------
template <int R>
__global__ __launch_bounds__(256)
void proto_main(const float* __restrict__ feats,
                const int* __restrict__ masks,
                float* __restrict__ psum,   // [B][NS][K][C]
                float* __restrict__ pcnt) { // [B][NS][K]
  constexpr int NS = NSRC / R;
  __shared__ __align__(16) float Wl[NK * R * 64];
  __shared__ int hist[NK];

  const int tid = threadIdx.x;
  const int strip = blockIdx.x;
  const int b = blockIdx.y;
  const int r0 = strip * R;

  for (int i = tid; i < NK * R * 64; i += 256) Wl[i] = 0.f;
  if (tid < NK) hist[tid] = 0;
  __syncthreads();

  // ---- Phase 1 ----
  int ylo = 4 * r0 - 2; if (ylo < 0) ylo = 0;
  int yhi = 4 * (r0 + R - 1) + 5; if (yhi > NOUT - 1) yhi = NOUT - 1;
  const int npix = (yhi - ylo + 1) * NOUT;
  const int own_lo = 4 * r0, own_hi = 4 * r0 + 4 * R;

  for (int i = tid; i < npix; i += 256) {
    const int x = i & (NOUT - 1);
    const int y = ylo + (i >> 8);
    const int lbl = masks[((size_t)b * NOUT + y) * NOUT + x];
    if ((unsigned)lbl < NK) {
      // y taps: src = 0.25*y - 0.375 (half-pixel, 4x)
      const int ry = y >> 2, py = y & 3;
      const int j0y = (py < 2) ? ry - 1 : ry;
      const float fy = (py == 0) ? 0.625f : (py == 1) ? 0.875f
                     : (py == 2) ? 0.125f : 0.375f;
      const int rx = x >> 2, px = x & 3;
      const int j0x = (px < 2) ? rx - 1 : rx;
      const float fx = (px == 0) ? 0.625f : (px == 1) ? 0.875f
                     : (px == 2) ? 0.125f : 0.375f;

      const int cx0 = (j0x < 0) ? 0 : j0x;
      const int cx1 = (j0x + 1 > NSRC - 1) ? NSRC - 1 : j0x + 1;
      const float wx0 = 1.f - fx, wx1 = fx;
      const int ry0 = (j0y < 0) ? 0 : j0y;
      const int ry1 = (j0y + 1 > NSRC - 1) ? NSRC - 1 : j0y + 1;
      const float wy0 = 1.f - fy, wy1 = fy;

      float* Wk = &Wl[lbl * (R * 64)];
      const int sr0 = ry0 - r0, sr1 = ry1 - r0;
      if (sr0 >= 0 && sr0 < R) {
        atomicAdd(&Wk[sr0 * 64 + cx0], wy0 * wx0);
        atomicAdd(&Wk[sr0 * 64 + cx1], wy0 * wx1);
      }
      if (sr1 >= 0 && sr1 < R) {
        atomicAdd(&Wk[sr1 * 64 + cx0], wy1 * wx0);
        atomicAdd(&Wk[sr1 * 64 + cx1], wy1 * wx1);
      }
      if (y >= own_lo && y < own_hi) atomicAdd(&hist[lbl], 1);
    }
  }
  __syncthreads();

  // ---- Phase 2 ----
  const int c = tid;
  const float4* fbase =
      (const float4*)(feats + ((size_t)(b * NC + c) << 12) + (size_t)r0 * 64);

  float acc[NK];
#pragma unroll
  for (int k = 0; k < NK; ++k) acc[k] = 0.f;

  for (int rr = 0; rr < R; ++rr) {
    float4 f[16];
#pragma unroll
    for (int j = 0; j < 16; ++j) f[j] = fbase[rr * 16 + j];  // one latency, 16 in flight
#pragma unroll
    for (int k = 0; k < NK; ++k) {
      const float4* w = (const float4*)&Wl[(k * R + rr) * 64];
      float a = acc[k];
#pragma unroll
      for (int j = 0; j < 16; ++j) {
        const float4 ww = w[j];  // broadcast ds_read_b128, conflict-free
        a = fmaf(f[j].x, ww.x, a);
        a = fmaf(f[j].y, ww.y, a);
        a = fmaf(f[j].z, ww.z, a);
        a = fmaf(f[j].w, ww.w, a);
      }
      acc[k] = a;
    }
  }

  float* dst = psum + ((size_t)(b * NS + strip) * NK) * NC + c;
#pragma unroll
  for (int k = 0; k < NK; ++k) dst[k * NC] = acc[k];
  if (tid < NK) pcnt[(size_t)(b * NS + strip) * NK + tid] = (float)hist[tid];
}

// Atomic-fallback main (only if ws is tiny): accumulates into psum[B][K][C].
__global__ __launch_bounds__(256)
void proto_main_atomic(const float* __restrict__ feats,
                       const int* __restrict__ masks,
                       float* __restrict__ psum,   // [B][K][C]
                       float* __restrict__ pcnt) { // [B][K]
  constexpr int R = 2;
  __shared__ __align__(16) float Wl[NK * R * 64];
  __shared__ int hist[NK];
  const int tid = threadIdx.x;
  const int strip = blockIdx.x;
  const int b = blockIdx.y;
  const int r0 = strip * R;

  for (int i = tid; i < NK * R * 64; i += 256) Wl[i] = 0.f;
  if (tid < NK) hist[tid] = 0;
  __syncthreads();

  int ylo = 4 * r0 - 2; if (ylo < 0) ylo = 0;
  int yhi = 4 * (r0 + R - 1) + 5; if (yhi > NOUT - 1) yhi = NOUT - 1;
  const int npix = (yhi - ylo + 1) * NOUT;
  const int own_lo = 4 * r0, own_hi = 4 * r0 + 4 * R;

  for (int i = tid; i < npix; i += 256) {
    const int x = i & (NOUT - 1);
    const int y = ylo + (i >> 8);
    const int lbl = masks[((size_t)b * NOUT + y) * NOUT + x];
    if ((unsigned)lbl < NK) {
      const int ry = y >> 2, py = y & 3;
      const int j0y = (py < 2) ? ry - 1 : ry;
      const float fy = (py == 0) ? 0.625f : (py == 1) ? 0.875f
                     : (py == 2) ? 0.125f : 0.375f;
      const int rx = x >> 2, px = x & 3;
      const int j0x = (px < 2) ? rx - 1 : rx;
      const float fx = (px == 0) ? 0.625f : (px == 1) ? 0.875f
                     : (px == 2) ? 0.125f : 0.375f;
      const int cx0 = (j0x < 0) ? 0 : j0x;
      const int cx1 = (j0x + 1 > NSRC - 1) ? NSRC - 1 : j0x + 1;
      const float wx0 = 1.f - fx, wx1 = fx;
      const int ry0 = (j0y < 0) ? 0 : j0y;
      const int ry1 = (j0y + 1 > NSRC - 1) ? NSRC - 1 : j0y + 1;
      const float wy0 = 1.f - fy, wy1 = fy;
      float* Wk = &Wl[lbl * (R * 64)];
      const int sr0 = ry0 - r0, sr1 = ry1 - r0;
      if (sr0 >= 0 && sr0 < R) {
        atomicAdd(&Wk[sr0 * 64 + cx0], wy0 * wx0);
        atomicAdd(&Wk[sr0 * 64 + cx1], wy0 * wx1);
      }
      if (sr1 >= 0 && sr1 < R) {
        atomicAdd(&Wk[sr1 * 64 + cx0], wy1 * wx0);
        atomicAdd(&Wk[sr1 * 64 + cx1], wy1 * wx1);
      }
      if (y >= own_lo && y < own_hi) atomicAdd(&hist[lbl], 1);
    }
  }
  __syncthreads();

  const int c = tid;
  const float4* fbase =
      (const float4*)(feats + ((size_t)(b * NC + c) << 12) + (size_t)r0 * 64);
  float acc[NK];
#pragma unroll
  for (int k = 0; k < NK; ++k) acc[k] = 0.f;
  for (int rr = 0; rr < R; ++rr) {
    float4 f[16];
#pragma unroll
    for (int j = 0; j < 16; ++j) f[j] = fbase[rr * 16 + j];
#pragma unroll
    for (int k = 0; k < NK; ++k) {
      const float4* w = (const float4*)&Wl[(k * R + rr) * 64];
      float a = acc[k];
#pragma unroll
      for (int j = 0; j < 16; ++j) {
        const float4 ww = w[j];
        a = fmaf(f[j].x, ww.x, a);
        a = fmaf(f[j].y, ww.y, a);
        a = fmaf(f[j].z, ww.z, a);
        a = fmaf(f[j].w, ww.w, a);
      }
      acc[k] = a;
    }
  }
#pragma unroll
  for (int k = 0; k < NK; ++k)
    atomicAdd(&psum[((size_t)b * NK + k) * NC + c], acc[k]);
  if (tid < NK) atomicAdd(&pcnt[(size_t)b * NK + tid], (float)hist[tid]);
}

// ---------------------------------------------------------------------------
// Finalize: grid (NK, NB); out[k][c] += sum_st psum / (sum_st cnt + eps) / 8
// ---------------------------------------------------------------------------
__global__ __launch_bounds__(256)
void proto_final(const float* __restrict__ psum,
                 const float* __restrict__ pcnt,
                 float* __restrict__ out, int ns) {
  const int k = blockIdx.x;   // 0..20
  const int b = blockIdx.y;   // 0..7
  const int c = threadIdx.x;  // 0..255
  float s = 0.f, cnt = 0.f;
  for (int st = 0; st < ns; ++st) {
    s += psum[((size_t)(b * ns + st) * NK + k) * NC + c];  // coalesced
    cnt += pcnt[(size_t)(b * ns + st) * NK + k];           // broadcast
  }
  atomicAdd(&out[k * NC + c], s / (cnt + EPS) * 0.125f);
}

extern "C" void kernel_launch(void* const* d_in, const int* in_sizes, int n_in,
                              void* d_out, int out_size, void* d_ws, size_t ws_size,
                              hipStream_t stream) {
  const float* feats = (const float*)d_in[0];
  const int* masks = (const int*)d_in[1];
  float* out = (float*)d_out;

  const size_t need1 = (size_t)NB * 64 * NK * (NC + 1) * 4;  // R=1: ~11.05 MB
  const size_t need2 = (size_t)NB * 32 * NK * (NC + 1) * 4;  // R=2: ~5.53 MB

  hipMemsetAsync(d_out, 0, (size_t)out_size * 4, stream);

  float* psum = (float*)d_ws;
  if (ws_size >= need1) {
    float* pcnt = psum + (size_t)NB * 64 * NK * NC;
    proto_main<1><<<dim3(64, NB), 256, 0, stream>>>(feats, masks, psum, pcnt);
    proto_final<<<dim3(NK, NB), 256, 0, stream>>>(psum, pcnt, out, 64);
  } else if (ws_size >= need2) {
    float* pcnt = psum + (size_t)NB * 32 * NK * NC;
    proto_main<2><<<dim3(32, NB), 256, 0, stream>>>(feats, masks, psum, pcnt);
    proto_final<<<dim3(NK, NB), 256, 0, stream>>>(psum, pcnt, out, 32);
  } else {
    float* pcnt = psum + (size_t)NB * NK * NC;
    hipMemsetAsync(d_ws, 0, ((size_t)NB * NK * NC + (size_t)NB * NK) * 4, stream);
    proto_main_atomic<<<dim3(32, NB), 256, 0, stream>>>(feats, masks, psum, pcnt);
    proto_final<<<dim3(NK, NB), 256, 0, stream>>>(psum, pcnt, out, 1);
  }
}